// Round 1
// baseline (1077.150 us; speedup 1.0000x reference)
//
#include <hip/hip_runtime.h>
#include <hip/hip_bf16.h>

typedef __bf16 bf16x8 __attribute__((ext_vector_type(8)));
typedef float  f32x4  __attribute__((ext_vector_type(4)));

#define T_   3
#define N_   200000
#define C_   256
#define B_   512
#define CAP  65536
#define EPSb 1e-5f

__device__ __forceinline__ unsigned enc_f(float f){
  unsigned u = __float_as_uint(f);
  return (u & 0x80000000u) ? ~u : (u | 0x80000000u);
}
__device__ __forceinline__ float dec_f(unsigned k){
  unsigned u = (k & 0x80000000u) ? (k ^ 0x80000000u) : ~k;
  return __uint_as_float(u);
}

// ---------------- init + prep (g=bias, Wl^T bf16, cvec = bl+br+gtok@Wr, zero accums)
__global__ void kinit(float* gout, const float* bout, unsigned* mkey, unsigned* mexkey,
                      float* den, int* cnt, float* bns,
                      const float* Wl, const float* Wr, const float* bl, const float* br,
                      const float* gtok, __hip_bfloat16* wlt, float* cvec){
  int idx = blockIdx.x*256 + threadIdx.x;
  int stride = gridDim.x*256;
  for (int i = idx; i < 393216; i += stride){
    int t = i >> 17, c = i & 255;
    gout[i] = bout[t*256 + c];
  }
  for (int i = idx; i < 196608; i += stride){
    int t = i >> 16, rem = i & 65535, c = rem >> 8, k = rem & 255;
    wlt[i] = __float2bfloat16(Wl[t*65536 + k*256 + c]);  // wlt[t][c][k]
  }
  for (int i = idx; i < 768; i += stride){
    int t = i >> 8, c = i & 255;
    float a = bl[i] + br[i];
    const float* wr = Wr + t*65536 + c;
    const float* gt = gtok + t*256;
    for (int k = 0; k < 256; k++) a += gt[k]*wr[k*256];
    cvec[i] = a;
  }
  for (int i = idx; i < 1536; i += stride){ mkey[i]=0u; mexkey[i]=0u; den[i]=0.f; }
  for (int i = idx; i < 2048; i += stride) bns[i] = 0.f;
  if (idx < 3) cnt[idx] = 0;
}

// ---------------- big pass: e_approx[t][n] = att . lrelu(x@Wl + cvec), bf16 MFMA
__global__ __launch_bounds__(512, 2)
void k1(const float* __restrict__ x, const __hip_bfloat16* __restrict__ wlt,
        const float* __restrict__ cvec, const float* __restrict__ att,
        const int* __restrict__ batch, float* __restrict__ e_out,
        unsigned* __restrict__ mkey){
  __shared__ __align__(16) __hip_bfloat16 Abuf[2][64][256];
  __shared__ float elds[4][64];
  const int t   = blockIdx.y;
  const int tid = threadIdx.x;
  const int w = tid >> 6, l = tid & 63;
  const int wcol = w & 3, wrow = w >> 2;
  const int l15 = l & 15, l4 = l >> 4;

  // B fragments: whole Wl^T (256 cols x 256 k) held in registers per wave-col-group
  bf16x8 bfr[8][4];
  float cv[4], at[4];
  const __hip_bfloat16* WT = wlt + t*65536;
  #pragma unroll
  for (int fn = 0; fn < 4; fn++){
    int col = wcol*64 + fn*16 + l15;
    cv[fn] = cvec[t*256 + col];
    at[fn] = att[t*256 + col];
    #pragma unroll
    for (int ks = 0; ks < 8; ks++)
      bfr[ks][fn] = *(const bf16x8*)(WT + col*256 + ks*32 + l4*8);
  }

  const int srow = tid >> 3;     // 0..63 row in tile
  const int sc   = tid & 7;      // chunk base
  const int sx   = srow & 7;     // xor swizzle
  const size_t xbase = (size_t)t * N_ * 256;
  const int tile0 = blockIdx.x * 5;

  f32x4 rg[8];
  {
    const float* xrow = x + xbase + (size_t)(tile0*64 + srow)*256;
    #pragma unroll
    for (int q = 0; q < 4; q++){
      int cs = (q*8 + sc) ^ sx;
      rg[2*q]   = *(const f32x4*)(xrow + cs*8);
      rg[2*q+1] = *(const f32x4*)(xrow + cs*8 + 4);
    }
  }

  for (int i = 0; i < 5; i++){
    const int tile = tile0 + i;
    // cvt + write LDS (swizzled slots: LDS[row][c] holds x[row][c ^ (row&7)])
    #pragma unroll
    for (int q = 0; q < 4; q++){
      bf16x8 v;
      #pragma unroll
      for (int j = 0; j < 4; j++){ v[j] = (__bf16)rg[2*q][j]; v[4+j] = (__bf16)rg[2*q+1][j]; }
      *(bf16x8*)(&Abuf[i&1][srow][(q*8 + sc)*8]) = v;
    }
    if (i < 4){
      const float* xrow = x + xbase + (size_t)((tile+1)*64 + srow)*256;
      #pragma unroll
      for (int q = 0; q < 4; q++){
        int cs = (q*8 + sc) ^ sx;
        rg[2*q]   = *(const f32x4*)(xrow + cs*8);
        rg[2*q+1] = *(const f32x4*)(xrow + cs*8 + 4);
      }
    }
    __syncthreads();

    f32x4 acc[2][4];
    #pragma unroll
    for (int fm = 0; fm < 2; fm++)
      #pragma unroll
      for (int fn = 0; fn < 4; fn++)
        acc[fm][fn] = (f32x4){0.f,0.f,0.f,0.f};

    #pragma unroll
    for (int ks = 0; ks < 8; ks++){
      bf16x8 a8[2];
      #pragma unroll
      for (int fm = 0; fm < 2; fm++){
        int row  = wrow*32 + fm*16 + l15;
        int slot = (ks*4 + l4) ^ (row & 7);
        a8[fm] = *(const bf16x8*)(&Abuf[i&1][row][slot*8]);
      }
      #pragma unroll
      for (int fm = 0; fm < 2; fm++)
        #pragma unroll
        for (int fn = 0; fn < 4; fn++)
          acc[fm][fn] = __builtin_amdgcn_mfma_f32_16x16x32_bf16(a8[fm], bfr[ks][fn], acc[fm][fn], 0, 0, 0);
    }

    // epilogue: leaky_relu + att dot + reduce over cols
    #pragma unroll
    for (int fm = 0; fm < 2; fm++){
      #pragma unroll
      for (int r = 0; r < 4; r++){
        float v = 0.f;
        #pragma unroll
        for (int fn = 0; fn < 4; fn++){
          float xv = acc[fm][fn][r] + cv[fn];
          xv = (xv > 0.f) ? xv : 0.2f*xv;
          v += xv * at[fn];
        }
        v += __shfl_xor(v, 1);
        v += __shfl_xor(v, 2);
        v += __shfl_xor(v, 4);
        v += __shfl_xor(v, 8);
        if (l15 == 0) elds[wcol][wrow*32 + fm*16 + l4*4 + r] = v;
      }
    }
    __syncthreads();
    if (tid < 64){
      float ef = elds[0][tid] + elds[1][tid] + elds[2][tid] + elds[3][tid];
      int n = tile*64 + tid;
      e_out[t*N_ + n] = ef;
      int b = batch[t*N_ + n];
      atomicMax(&mkey[t*B_ + b], enc_f(ef));
    }
  }
}

// ---------------- candidate selection: e >= segmax - 30
__global__ void kselect(const float* __restrict__ e, const int* __restrict__ batch,
                        const unsigned* __restrict__ mkey, int* cnt, int* list){
  int t = blockIdx.y;
  int n = blockIdx.x*256 + threadIdx.x;
  if (n >= N_) return;
  float ev = e[t*N_ + n];
  int b = batch[t*N_ + n];
  float m = dec_f(mkey[t*B_ + b]);
  if (ev >= m - 30.0f){
    int pos = atomicAdd(&cnt[t], 1);
    if (pos < CAP) list[t*CAP + pos] = n;
  }
}

// ---------------- exact fp32 e for candidates
__global__ void kexact(const float* __restrict__ x, const float* __restrict__ Wl,
                       const float* __restrict__ cvec, const float* __restrict__ att,
                       const int* __restrict__ batch, const int* __restrict__ cnt,
                       const int* __restrict__ list, float* __restrict__ eex,
                       unsigned* __restrict__ mexkey){
  __shared__ float xs[256];
  __shared__ float red[4];
  int t = blockIdx.y;
  int c = threadIdx.x;
  int nc = min(cnt[t], CAP);
  for (int ci = blockIdx.x; ci < nc; ci += gridDim.x){
    int n = list[t*CAP + ci];
    xs[c] = x[(size_t)t*N_*256 + (size_t)n*256 + c];
    __syncthreads();
    const float* wp = Wl + t*65536 + c;
    float a0 = 0.f, a1 = 0.f;
    #pragma unroll 8
    for (int k = 0; k < 256; k += 2){
      a0 += xs[k]   * wp[k*256];
      a1 += xs[k+1] * wp[(k+1)*256];
    }
    float xv = a0 + a1 + cvec[t*256 + c];
    xv = (xv > 0.f) ? xv : 0.2f*xv;
    float term = xv * att[t*256 + c];
    #pragma unroll
    for (int off = 1; off < 64; off <<= 1) term += __shfl_xor(term, off);
    if ((c & 63) == 0) red[c >> 6] = term;
    __syncthreads();
    if (c == 0){
      float ev = red[0] + red[1] + red[2] + red[3];
      eex[t*CAP + ci] = ev;
      atomicMax(&mexkey[t*B_ + batch[t*N_ + n]], enc_f(ev));
    }
    __syncthreads();
  }
}

// ---------------- denominator
__global__ void kden(const int* __restrict__ cnt, const int* __restrict__ list,
                     const float* __restrict__ eex, const int* __restrict__ batch,
                     const unsigned* __restrict__ mexkey, float* __restrict__ den){
  int t = blockIdx.y;
  int nc = min(cnt[t], CAP);
  for (int ci = blockIdx.x*256 + threadIdx.x; ci < nc; ci += gridDim.x*256){
    int n = list[t*CAP + ci];
    int b = batch[t*N_ + n];
    float m = dec_f(mexkey[t*B_ + b]);
    atomicAdd(&den[t*B_ + b], expf(eex[t*CAP + ci] - m));
  }
}

// ---------------- g accumulation (exact fp32 xl, alpha-weighted)
__global__ void kaccum(const float* __restrict__ x, const float* __restrict__ Wl,
                       const float* __restrict__ bl, const int* __restrict__ batch,
                       const int* __restrict__ cnt, const int* __restrict__ list,
                       const float* __restrict__ eex, const unsigned* __restrict__ mexkey,
                       const float* __restrict__ den, float* __restrict__ gout){
  __shared__ float xs[256];
  int t = blockIdx.y;
  int c = threadIdx.x;
  int nc = min(cnt[t], CAP);
  for (int ci = blockIdx.x; ci < nc; ci += gridDim.x){
    int n = list[t*CAP + ci];
    xs[c] = x[(size_t)t*N_*256 + (size_t)n*256 + c];
    __syncthreads();
    const float* wp = Wl + t*65536 + c;
    float a0 = 0.f, a1 = 0.f;
    #pragma unroll 8
    for (int k = 0; k < 256; k += 2){
      a0 += xs[k]   * wp[k*256];
      a1 += xs[k+1] * wp[(k+1)*256];
    }
    int b = batch[t*N_ + n];
    float m = dec_f(mexkey[t*B_ + b]);
    float wgt = expf(eex[t*CAP + ci] - m) / den[t*B_ + b];
    atomicAdd(&gout[t*131072 + b*256 + c], wgt * (a0 + a1 + bl[t*256 + c]));
    __syncthreads();
  }
}

// ---------------- head: concat
__global__ void kconcat(const float* __restrict__ ga, const float* __restrict__ g,
                        float* __restrict__ h0){
  int b = blockIdx.x;
  for (int col = threadIdx.x; col < 832; col += 256){
    float v;
    if (col < 64) v = ga[b*64 + col];
    else { int t = (col - 64) >> 8; int c = (col - 64) & 255; v = g[t*131072 + b*256 + c]; }
    h0[b*832 + col] = v;
  }
}

// ---------------- head: generic fp32 GEMM  out = [tanh](A@W + bias [+ addm])
__global__ __launch_bounds__(256)
void kgemm(const float* __restrict__ A, const float* __restrict__ W,
           const float* __restrict__ bias, const float* __restrict__ addm,
           float* __restrict__ out, int M, int N, int K, int dotanh){
  __shared__ float As[32][17];
  __shared__ float Ws[16][64];
  int tx = threadIdx.x & 15, ty = threadIdx.x >> 4;
  int row0 = blockIdx.y * 32, col0 = blockIdx.x * 64;
  float acc[2][4] = {};
  for (int k0 = 0; k0 < K; k0 += 16){
    #pragma unroll
    for (int q = 0; q < 2; q++){
      int e = threadIdx.x + q*256;
      int r = e >> 4, kk = e & 15;
      As[r][kk] = A[(size_t)(row0 + r)*K + k0 + kk];
    }
    #pragma unroll
    for (int q = 0; q < 4; q++){
      int e = threadIdx.x + q*256;
      int kr = e >> 6, cc = e & 63;
      Ws[kr][cc] = W[(size_t)(k0 + kr)*N + col0 + cc];
    }
    __syncthreads();
    #pragma unroll
    for (int kk = 0; kk < 16; kk++){
      float a0 = As[ty][kk], a1 = As[ty + 16][kk];
      #pragma unroll
      for (int j = 0; j < 4; j++){
        float wv = Ws[kk][tx + j*16];
        acc[0][j] += a0*wv;
        acc[1][j] += a1*wv;
      }
    }
    __syncthreads();
  }
  #pragma unroll
  for (int i2 = 0; i2 < 2; i2++){
    int row = row0 + ty + i2*16;
    #pragma unroll
    for (int j = 0; j < 4; j++){
      int col = col0 + tx + j*16;
      float v = acc[i2][j] + bias[col];
      if (addm) v += addm[(size_t)row*N + col];
      if (dotanh) v = tanhf(v);
      out[(size_t)row*N + col] = v;
    }
  }
}

// ---------------- head: BN stats (sum, sumsq per column, H=512)
__global__ void kbnstats(const float* __restrict__ Hm, float* __restrict__ sums){
  int c = threadIdx.x;           // 512 threads
  int r0 = blockIdx.x * 64;
  float s = 0.f, s2 = 0.f;
  for (int r = r0; r < r0 + 64; r++){
    float v = Hm[r*512 + c];
    s += v; s2 += v*v;
  }
  atomicAdd(&sums[c], s);
  atomicAdd(&sums[512 + c], s2);
}

// ---------------- head: BN apply + tanh
__global__ void kbnapply(const float* __restrict__ Hm, const float* __restrict__ sums,
                         const float* __restrict__ gam, const float* __restrict__ bet,
                         float* __restrict__ outm){
  int idx = blockIdx.x*256 + threadIdx.x;
  if (idx >= 512*512) return;
  int c = idx & 511;
  float mu  = sums[c] * (1.f/512.f);
  float var = sums[512 + c] * (1.f/512.f) - mu*mu;
  float inv = 1.f / sqrtf(var + EPSb);
  float v = (Hm[idx] - mu) * inv * gam[c] + bet[c];
  outm[idx] = tanhf(v);
}

extern "C" void kernel_launch(void* const* d_in, const int* in_sizes, int n_in,
                              void* d_out, int out_size, void* d_ws, size_t ws_size,
                              hipStream_t stream){
  const float* x    = (const float*)d_in[0];
  const float* ga   = (const float*)d_in[1];
  const float* Wl   = (const float*)d_in[2];
  const float* bl   = (const float*)d_in[3];
  const float* Wr   = (const float*)d_in[4];
  const float* br   = (const float*)d_in[5];
  const float* att  = (const float*)d_in[6];
  const float* bout = (const float*)d_in[7];
  const float* gtok = (const float*)d_in[8];
  const float* m1pw = (const float*)d_in[9];
  const float* m1pb = (const float*)d_in[10];
  const float* m1w1 = (const float*)d_in[11];
  const float* m1b1 = (const float*)d_in[12];
  const float* m1w2 = (const float*)d_in[13];
  const float* m1b2 = (const float*)d_in[14];
  const float* bn1g = (const float*)d_in[15];
  const float* bn1b = (const float*)d_in[16];
  const float* m2w1 = (const float*)d_in[17];
  const float* m2b1 = (const float*)d_in[18];
  const float* m2w2 = (const float*)d_in[19];
  const float* m2b2 = (const float*)d_in[20];
  const float* bn2g = (const float*)d_in[21];
  const float* bn2b = (const float*)d_in[22];
  const float* m3pw = (const float*)d_in[23];
  const float* m3pb = (const float*)d_in[24];
  const float* m3w1 = (const float*)d_in[25];
  const float* m3b1 = (const float*)d_in[26];
  const float* m3w2 = (const float*)d_in[27];
  const float* m3b2 = (const float*)d_in[28];
  const int*   batch= (const int*)d_in[29];

  float* gout = (float*)d_out;              // [3][512][256]
  float* hout = (float*)d_out + 393216;     // [512][256]

  char* w = (char*)d_ws;
  __hip_bfloat16* wlt = (__hip_bfloat16*)(w + 0);        // 393216 B
  float*    cvec   = (float*)(w + 393216);               // 3072
  float*    ebuf   = (float*)(w + 396288);               // 2400000
  unsigned* mkey   = (unsigned*)(w + 2796288);           // 6144
  unsigned* mexkey = (unsigned*)(w + 2802432);           // 6144
  float*    den    = (float*)(w + 2808576);              // 6144
  int*      cnt    = (int*)(w + 2814720);                // 64
  int*      list   = (int*)(w + 2814784);                // 786432
  float*    eex    = (float*)(w + 3601216);              // 786432
  float*    h0     = (float*)(w + 4387648);              // 1703936
  float*    T1     = (float*)(w + 6091584);              // 1048576
  float*    P1     = (float*)(w + 7140160);              // 1048576
  float*    Hm     = (float*)(w + 8188736);              // 1048576
  float*    HB1    = (float*)(w + 9237312);              // 1048576
  float*    H2     = (float*)(w + 10285888);             // 1048576
  float*    HB2    = (float*)(w + 11334464);             // 1048576
  float*    T3     = (float*)(w + 12383040);             // 524288
  float*    P3     = (float*)(w + 12907328);             // 524288
  float*    bns    = (float*)(w + 13431616);             // 8192 (bn1: 1024 fl, bn2: 1024 fl)

  kinit<<<1536, 256, 0, stream>>>(gout, bout, mkey, mexkey, den, cnt, bns,
                                  Wl, Wr, bl, br, gtok, wlt, cvec);
  k1<<<dim3(625, 3), 512, 0, stream>>>(x, wlt, cvec, att, batch, ebuf, mkey);
  kselect<<<dim3(782, 3), 256, 0, stream>>>(ebuf, batch, mkey, cnt, list);
  kexact<<<dim3(128, 3), 256, 0, stream>>>(x, Wl, cvec, att, batch, cnt, list, eex, mexkey);
  kden<<<dim3(8, 3), 256, 0, stream>>>(cnt, list, eex, batch, mexkey, den);
  kaccum<<<dim3(128, 3), 256, 0, stream>>>(x, Wl, bl, batch, cnt, list, eex, mexkey, den, gout);
  kconcat<<<512, 256, 0, stream>>>(ga, gout, h0);
  kgemm<<<dim3(8, 16), 256, 0, stream>>>(h0, m1w1, m1b1, nullptr, T1, 512, 512, 832, 1);
  kgemm<<<dim3(8, 16), 256, 0, stream>>>(h0, m1pw, m1pb, nullptr, P1, 512, 512, 832, 0);
  kgemm<<<dim3(8, 16), 256, 0, stream>>>(T1, m1w2, m1b2, P1, Hm, 512, 512, 512, 0);
  kbnstats<<<8, 512, 0, stream>>>(Hm, bns);
  kbnapply<<<1024, 256, 0, stream>>>(Hm, bns, bn1g, bn1b, HB1);
  kgemm<<<dim3(8, 16), 256, 0, stream>>>(HB1, m2w1, m2b1, nullptr, T1, 512, 512, 512, 1);
  kgemm<<<dim3(8, 16), 256, 0, stream>>>(T1, m2w2, m2b2, HB1, H2, 512, 512, 512, 0);
  kbnstats<<<8, 512, 0, stream>>>(H2, bns + 1024);
  kbnapply<<<1024, 256, 0, stream>>>(H2, bns + 1024, bn2g, bn2b, HB2);
  kgemm<<<dim3(4, 16), 256, 0, stream>>>(HB2, m3w1, m3b1, nullptr, T3, 512, 256, 512, 1);
  kgemm<<<dim3(4, 16), 256, 0, stream>>>(HB2, m3pw, m3pb, nullptr, P3, 512, 256, 512, 0);
  kgemm<<<dim3(4, 16), 256, 0, stream>>>(T3, m3w2, m3b2, P3, hout, 512, 256, 256, 0);
}

// Round 2
// 632.302 us; speedup vs baseline: 1.7035x; 1.7035x over previous
//
#include <hip/hip_runtime.h>
#include <hip/hip_bf16.h>

typedef __bf16 bf16x8 __attribute__((ext_vector_type(8)));
typedef float  f32x4  __attribute__((ext_vector_type(4)));

#define T_   3
#define N_   200000
#define C_   256
#define B_   512
#define CAP  65536
#define EPSb 1e-5f

__device__ __forceinline__ unsigned enc_f(float f){
  unsigned u = __float_as_uint(f);
  return (u & 0x80000000u) ? ~u : (u | 0x80000000u);
}
__device__ __forceinline__ float dec_f(unsigned k){
  unsigned u = (k & 0x80000000u) ? (k ^ 0x80000000u) : ~k;
  return __uint_as_float(u);
}

// raw barrier WITHOUT vmcnt drain: lets prefetch global loads stay in flight
// across the barrier (the __syncthreads() vmcnt(0) drain was the k1 serializer).
__device__ __forceinline__ void barrier_nodrain(){
  __builtin_amdgcn_sched_barrier(0);
  asm volatile("s_waitcnt lgkmcnt(0)" ::: "memory");
  __builtin_amdgcn_s_barrier();
  __builtin_amdgcn_sched_barrier(0);
}

// ---------------- init (g=bias, cvec = bl+br+gtok@Wr, zero accums)
__global__ void kinit(float* gout, const float* bout, unsigned* mkey, unsigned* mexkey,
                      float* den, int* cnt, float* bns,
                      const float* Wr, const float* bl, const float* br,
                      const float* gtok, float* cvec){
  int idx = blockIdx.x*256 + threadIdx.x;
  int stride = gridDim.x*256;
  for (int i = idx; i < 393216; i += stride){
    int t = i >> 17, c = i & 255;
    gout[i] = bout[t*256 + c];
  }
  for (int i = idx; i < 768; i += stride){
    int t = i >> 8, c = i & 255;
    float a = bl[i] + br[i];
    const float* wr = Wr + t*65536 + c;
    const float* gt = gtok + t*256;
    for (int k = 0; k < 256; k++) a += gt[k]*wr[k*256];   // coalesced across c
    cvec[i] = a;
  }
  for (int i = idx; i < 1536; i += stride){ mkey[i]=0u; mexkey[i]=0u; den[i]=0.f; }
  for (int i = idx; i < 2048; i += stride) bns[i] = 0.f;
  if (idx < 3) cnt[idx] = 0;
}

// ---------------- Wl[t][k][c] -> wlt[t][c][k] bf16, LDS-tiled (both sides coalesced)
__global__ void ktrans(const float* __restrict__ Wl, __hip_bfloat16* __restrict__ wlt){
  __shared__ float tile[64][65];
  int t = blockIdx.z;
  int k0 = blockIdx.y*64, c0 = blockIdx.x*64;
  int lc = threadIdx.x & 63;
  int lr0 = threadIdx.x >> 6;
  #pragma unroll
  for (int q = 0; q < 16; q++){
    int lr = lr0*16 + q;
    tile[lr][lc] = Wl[t*65536 + (k0+lr)*256 + (c0+lc)];
  }
  __syncthreads();
  #pragma unroll
  for (int q = 0; q < 16; q++){
    int lr = lr0*16 + q;
    wlt[t*65536 + (c0+lr)*256 + (k0+lc)] = __float2bfloat16(tile[lc][lr]);
  }
}

// ---------------- big pass: e_approx[t][n] = att . lrelu(x@Wl + cvec), bf16 MFMA
__global__ __launch_bounds__(512, 2)
void k1(const float* __restrict__ x, const __hip_bfloat16* __restrict__ wlt,
        const float* __restrict__ cvec, const float* __restrict__ att,
        const int* __restrict__ batch, float* __restrict__ e_out,
        unsigned* __restrict__ mkey){
  __shared__ __align__(16) __hip_bfloat16 Abuf[64][256];
  __shared__ float elds[4][64];
  const int t   = blockIdx.y;
  const int tid = threadIdx.x;
  const int w = tid >> 6, l = tid & 63;
  const int wcol = w & 3, wrow = w >> 2;
  const int l15 = l & 15, l4 = l >> 4;

  // whole Wl^T held in registers (B fragments), L2-hot
  bf16x8 bfr[8][4];
  float cv[4], at[4];
  const __hip_bfloat16* WT = wlt + t*65536;
  #pragma unroll
  for (int fn = 0; fn < 4; fn++){
    int col = wcol*64 + fn*16 + l15;
    cv[fn] = cvec[t*256 + col];
    at[fn] = att[t*256 + col];
    #pragma unroll
    for (int ks = 0; ks < 8; ks++)
      bfr[ks][fn] = *(const bf16x8*)(WT + col*256 + ks*32 + l4*8);
  }

  const int srow = tid >> 3;
  const int sc   = tid & 7;
  const int sx   = srow & 7;
  const size_t xbase = (size_t)t * N_ * 256;
  const int tile0 = blockIdx.x * 5;

  f32x4 rg[8];
  {
    const float* xrow = x + xbase + (size_t)(tile0*64 + srow)*256;
    #pragma unroll
    for (int q = 0; q < 4; q++){
      int cs = (q*8 + sc) ^ sx;
      rg[2*q]   = *(const f32x4*)(xrow + cs*8);
      rg[2*q+1] = *(const f32x4*)(xrow + cs*8 + 4);
    }
  }

  for (int i = 0; i < 5; i++){
    const int tile = tile0 + i;
    // cvt + LDS write (swizzled slots); compiler inserts vmcnt waits on rg
    #pragma unroll
    for (int q = 0; q < 4; q++){
      bf16x8 v;
      #pragma unroll
      for (int j = 0; j < 4; j++){ v[j] = (__bf16)rg[2*q][j]; v[4+j] = (__bf16)rg[2*q+1][j]; }
      *(bf16x8*)(&Abuf[srow][(q*8 + sc)*8]) = v;
    }
    // issue next-tile prefetch: stays in flight across the raw barrier,
    // consumed at next iteration's LDS write (latency hidden under MFMA)
    if (i < 4){
      const float* xrow = x + xbase + (size_t)((tile+1)*64 + srow)*256;
      #pragma unroll
      for (int q = 0; q < 4; q++){
        int cs = (q*8 + sc) ^ sx;
        rg[2*q]   = *(const f32x4*)(xrow + cs*8);
        rg[2*q+1] = *(const f32x4*)(xrow + cs*8 + 4);
      }
    }
    barrier_nodrain();   // Abuf visible, NO vmcnt drain

    f32x4 acc[2][4];
    #pragma unroll
    for (int fm = 0; fm < 2; fm++)
      #pragma unroll
      for (int fn = 0; fn < 4; fn++)
        acc[fm][fn] = (f32x4){0.f,0.f,0.f,0.f};

    #pragma unroll
    for (int ks = 0; ks < 8; ks++){
      bf16x8 a8[2];
      #pragma unroll
      for (int fm = 0; fm < 2; fm++){
        int row  = wrow*32 + fm*16 + l15;
        int slot = (ks*4 + l4) ^ (row & 7);
        a8[fm] = *(const bf16x8*)(&Abuf[row][slot*8]);
      }
      #pragma unroll
      for (int fm = 0; fm < 2; fm++)
        #pragma unroll
        for (int fn = 0; fn < 4; fn++)
          acc[fm][fn] = __builtin_amdgcn_mfma_f32_16x16x32_bf16(a8[fm], bfr[ks][fn], acc[fm][fn], 0, 0, 0);
    }

    // epilogue: leaky_relu + att dot + per-wave reduce
    #pragma unroll
    for (int fm = 0; fm < 2; fm++){
      #pragma unroll
      for (int r = 0; r < 4; r++){
        float v = 0.f;
        #pragma unroll
        for (int fn = 0; fn < 4; fn++){
          float xv = acc[fm][fn][r] + cv[fn];
          xv = (xv > 0.f) ? xv : 0.2f*xv;
          v += xv * at[fn];
        }
        v += __shfl_xor(v, 1);
        v += __shfl_xor(v, 2);
        v += __shfl_xor(v, 4);
        v += __shfl_xor(v, 8);
        if (l15 == 0) elds[wcol][wrow*32 + fm*16 + l4*4 + r] = v;
      }
    }
    barrier_nodrain();   // elds visible; all Abuf reads drained -> safe to overwrite

    if (tid < 64){
      float ef = elds[0][tid] + elds[1][tid] + elds[2][tid] + elds[3][tid];
      int n = tile*64 + tid;
      e_out[t*N_ + n] = ef;
      int b = batch[t*N_ + n];
      // segmented max-scan over sorted b: only run-boundary lanes issue atomics
      float m = ef;
      #pragma unroll
      for (int off = 1; off < 64; off <<= 1){
        float up = __shfl_up(m, off);
        int   bu = __shfl_up(b, off);
        if (tid >= off && bu == b) m = fmaxf(m, up);
      }
      int bnx = __shfl_down(b, 1);
      if (tid == 63 || b != bnx) atomicMax(&mkey[t*B_ + b], enc_f(m));
    }
  }
}

// ---------------- candidate selection: e >= segmax - 30
__global__ void kselect(const float* __restrict__ e, const int* __restrict__ batch,
                        const unsigned* __restrict__ mkey, int* cnt, int* list){
  int t = blockIdx.y;
  int n = blockIdx.x*256 + threadIdx.x;
  if (n >= N_) return;
  float ev = e[t*N_ + n];
  int b = batch[t*N_ + n];
  float m = dec_f(mkey[t*B_ + b]);
  if (ev >= m - 30.0f){
    int pos = atomicAdd(&cnt[t], 1);
    if (pos < CAP) list[t*CAP + pos] = n;
  }
}

// ---------------- exact fp32 e for candidates
__global__ void kexact(const float* __restrict__ x, const float* __restrict__ Wl,
                       const float* __restrict__ cvec, const float* __restrict__ att,
                       const int* __restrict__ batch, const int* __restrict__ cnt,
                       const int* __restrict__ list, float* __restrict__ eex,
                       unsigned* __restrict__ mexkey){
  __shared__ float xs[256];
  __shared__ float red[4];
  int t = blockIdx.y;
  int c = threadIdx.x;
  int nc = min(cnt[t], CAP);
  for (int ci = blockIdx.x; ci < nc; ci += gridDim.x){
    int n = list[t*CAP + ci];
    xs[c] = x[(size_t)t*N_*256 + (size_t)n*256 + c];
    __syncthreads();
    const float* wp = Wl + t*65536 + c;
    float a0 = 0.f, a1 = 0.f;
    #pragma unroll 8
    for (int k = 0; k < 256; k += 2){
      a0 += xs[k]   * wp[k*256];
      a1 += xs[k+1] * wp[(k+1)*256];
    }
    float xv = a0 + a1 + cvec[t*256 + c];
    xv = (xv > 0.f) ? xv : 0.2f*xv;
    float term = xv * att[t*256 + c];
    #pragma unroll
    for (int off = 1; off < 64; off <<= 1) term += __shfl_xor(term, off);
    if ((c & 63) == 0) red[c >> 6] = term;
    __syncthreads();
    if (c == 0){
      float ev = red[0] + red[1] + red[2] + red[3];
      eex[t*CAP + ci] = ev;
      atomicMax(&mexkey[t*B_ + batch[t*N_ + n]], enc_f(ev));
    }
    __syncthreads();
  }
}

// ---------------- denominator
__global__ void kden(const int* __restrict__ cnt, const int* __restrict__ list,
                     const float* __restrict__ eex, const int* __restrict__ batch,
                     const unsigned* __restrict__ mexkey, float* __restrict__ den){
  int t = blockIdx.y;
  int nc = min(cnt[t], CAP);
  for (int ci = blockIdx.x*256 + threadIdx.x; ci < nc; ci += gridDim.x*256){
    int n = list[t*CAP + ci];
    int b = batch[t*N_ + n];
    float m = dec_f(mexkey[t*B_ + b]);
    atomicAdd(&den[t*B_ + b], expf(eex[t*CAP + ci] - m));
  }
}

// ---------------- g accumulation (exact fp32 xl, alpha-weighted)
__global__ void kaccum(const float* __restrict__ x, const float* __restrict__ Wl,
                       const float* __restrict__ bl, const int* __restrict__ batch,
                       const int* __restrict__ cnt, const int* __restrict__ list,
                       const float* __restrict__ eex, const unsigned* __restrict__ mexkey,
                       const float* __restrict__ den, float* __restrict__ gout){
  __shared__ float xs[256];
  int t = blockIdx.y;
  int c = threadIdx.x;
  int nc = min(cnt[t], CAP);
  for (int ci = blockIdx.x; ci < nc; ci += gridDim.x){
    int n = list[t*CAP + ci];
    xs[c] = x[(size_t)t*N_*256 + (size_t)n*256 + c];
    __syncthreads();
    const float* wp = Wl + t*65536 + c;
    float a0 = 0.f, a1 = 0.f;
    #pragma unroll 8
    for (int k = 0; k < 256; k += 2){
      a0 += xs[k]   * wp[k*256];
      a1 += xs[k+1] * wp[(k+1)*256];
    }
    int b = batch[t*N_ + n];
    float m = dec_f(mexkey[t*B_ + b]);
    float wgt = expf(eex[t*CAP + ci] - m) / den[t*B_ + b];
    atomicAdd(&gout[t*131072 + b*256 + c], wgt * (a0 + a1 + bl[t*256 + c]));
    __syncthreads();
  }
}

// ---------------- head: concat
__global__ void kconcat(const float* __restrict__ ga, const float* __restrict__ g,
                        float* __restrict__ h0){
  int b = blockIdx.x;
  for (int col = threadIdx.x; col < 832; col += 256){
    float v;
    if (col < 64) v = ga[b*64 + col];
    else { int t = (col - 64) >> 8; int c = (col - 64) & 255; v = g[t*131072 + b*256 + c]; }
    h0[b*832 + col] = v;
  }
}

// ---------------- head: fp32 GEMM (dual weight-set via blockIdx.z)
__global__ __launch_bounds__(256)
void kgemm(const float* __restrict__ A,
           const float* __restrict__ W0, const float* __restrict__ bias0,
           const float* __restrict__ add0, float* __restrict__ out0, int tanh0,
           const float* __restrict__ W1, const float* __restrict__ bias1,
           const float* __restrict__ add1, float* __restrict__ out1, int tanh1,
           int M, int N, int K){
  const float* W = W0; const float* bias = bias0; const float* add = add0;
  float* out = out0; int dotanh = tanh0;
  if (blockIdx.z){ W = W1; bias = bias1; add = add1; out = out1; dotanh = tanh1; }
  __shared__ float As[32][17];
  __shared__ float Ws[16][64];
  int tx = threadIdx.x & 15, ty = threadIdx.x >> 4;
  int row0 = blockIdx.y * 32, col0 = blockIdx.x * 64;
  float acc[2][4] = {};
  for (int k0 = 0; k0 < K; k0 += 16){
    #pragma unroll
    for (int q = 0; q < 2; q++){
      int e = threadIdx.x + q*256;
      int r = e >> 4, kk = e & 15;
      As[r][kk] = A[(size_t)(row0 + r)*K + k0 + kk];
    }
    #pragma unroll
    for (int q = 0; q < 4; q++){
      int e = threadIdx.x + q*256;
      int kr = e >> 6, cc = e & 63;
      Ws[kr][cc] = W[(size_t)(k0 + kr)*N + col0 + cc];
    }
    __syncthreads();
    #pragma unroll
    for (int kk = 0; kk < 16; kk++){
      float a0 = As[ty][kk], a1 = As[ty + 16][kk];
      #pragma unroll
      for (int j = 0; j < 4; j++){
        float wv = Ws[kk][tx + j*16];
        acc[0][j] += a0*wv;
        acc[1][j] += a1*wv;
      }
    }
    __syncthreads();
  }
  #pragma unroll
  for (int i2 = 0; i2 < 2; i2++){
    int row = row0 + ty + i2*16;
    #pragma unroll
    for (int j = 0; j < 4; j++){
      int col = col0 + tx + j*16;
      float v = acc[i2][j] + bias[col];
      if (add) v += add[(size_t)row*N + col];
      if (dotanh) v = tanhf(v);
      out[(size_t)row*N + col] = v;
    }
  }
}

// ---------------- head: BN stats
__global__ void kbnstats(const float* __restrict__ Hm, float* __restrict__ sums){
  int c = threadIdx.x;
  int r0 = blockIdx.x * 64;
  float s = 0.f, s2 = 0.f;
  for (int r = r0; r < r0 + 64; r++){
    float v = Hm[r*512 + c];
    s += v; s2 += v*v;
  }
  atomicAdd(&sums[c], s);
  atomicAdd(&sums[512 + c], s2);
}

// ---------------- head: BN apply + tanh
__global__ void kbnapply(const float* __restrict__ Hm, const float* __restrict__ sums,
                         const float* __restrict__ gam, const float* __restrict__ bet,
                         float* __restrict__ outm){
  int idx = blockIdx.x*256 + threadIdx.x;
  if (idx >= 512*512) return;
  int c = idx & 511;
  float mu  = sums[c] * (1.f/512.f);
  float var = sums[512 + c] * (1.f/512.f) - mu*mu;
  float inv = 1.f / sqrtf(var + EPSb);
  float v = (Hm[idx] - mu) * inv * gam[c] + bet[c];
  outm[idx] = tanhf(v);
}

extern "C" void kernel_launch(void* const* d_in, const int* in_sizes, int n_in,
                              void* d_out, int out_size, void* d_ws, size_t ws_size,
                              hipStream_t stream){
  const float* x    = (const float*)d_in[0];
  const float* ga   = (const float*)d_in[1];
  const float* Wl   = (const float*)d_in[2];
  const float* bl   = (const float*)d_in[3];
  const float* Wr   = (const float*)d_in[4];
  const float* br   = (const float*)d_in[5];
  const float* att  = (const float*)d_in[6];
  const float* bout = (const float*)d_in[7];
  const float* gtok = (const float*)d_in[8];
  const float* m1pw = (const float*)d_in[9];
  const float* m1pb = (const float*)d_in[10];
  const float* m1w1 = (const float*)d_in[11];
  const float* m1b1 = (const float*)d_in[12];
  const float* m1w2 = (const float*)d_in[13];
  const float* m1b2 = (const float*)d_in[14];
  const float* bn1g = (const float*)d_in[15];
  const float* bn1b = (const float*)d_in[16];
  const float* m2w1 = (const float*)d_in[17];
  const float* m2b1 = (const float*)d_in[18];
  const float* m2w2 = (const float*)d_in[19];
  const float* m2b2 = (const float*)d_in[20];
  const float* bn2g = (const float*)d_in[21];
  const float* bn2b = (const float*)d_in[22];
  const float* m3pw = (const float*)d_in[23];
  const float* m3pb = (const float*)d_in[24];
  const float* m3w1 = (const float*)d_in[25];
  const float* m3b1 = (const float*)d_in[26];
  const float* m3w2 = (const float*)d_in[27];
  const float* m3b2 = (const float*)d_in[28];
  const int*   batch= (const int*)d_in[29];

  float* gout = (float*)d_out;              // [3][512][256]
  float* hout = (float*)d_out + 393216;     // [512][256]

  char* w = (char*)d_ws;
  __hip_bfloat16* wlt = (__hip_bfloat16*)(w + 0);        // 393216 B
  float*    cvec   = (float*)(w + 393216);
  float*    ebuf   = (float*)(w + 396288);
  unsigned* mkey   = (unsigned*)(w + 2796288);
  unsigned* mexkey = (unsigned*)(w + 2802432);
  float*    den    = (float*)(w + 2808576);
  int*      cnt    = (int*)(w + 2814720);
  int*      list   = (int*)(w + 2814784);
  float*    eex    = (float*)(w + 3601216);
  float*    h0     = (float*)(w + 4387648);
  float*    T1     = (float*)(w + 6091584);
  float*    P1     = (float*)(w + 7140160);
  float*    Hm     = (float*)(w + 8188736);
  float*    HB1    = (float*)(w + 9237312);
  float*    H2     = (float*)(w + 10285888);
  float*    HB2    = (float*)(w + 11334464);
  float*    T3     = (float*)(w + 12383040);
  float*    P3     = (float*)(w + 12907328);
  float*    bns    = (float*)(w + 13431616);

  kinit<<<1536, 256, 0, stream>>>(gout, bout, mkey, mexkey, den, cnt, bns,
                                  Wr, bl, br, gtok, cvec);
  ktrans<<<dim3(4, 4, 3), 256, 0, stream>>>(Wl, wlt);
  k1<<<dim3(625, 3), 512, 0, stream>>>(x, wlt, cvec, att, batch, ebuf, mkey);
  kselect<<<dim3(782, 3), 256, 0, stream>>>(ebuf, batch, mkey, cnt, list);
  kexact<<<dim3(128, 3), 256, 0, stream>>>(x, Wl, cvec, att, batch, cnt, list, eex, mexkey);
  kden<<<dim3(8, 3), 256, 0, stream>>>(cnt, list, eex, batch, mexkey, den);
  kaccum<<<dim3(128, 3), 256, 0, stream>>>(x, Wl, bl, batch, cnt, list, eex, mexkey, den, gout);
  kconcat<<<512, 256, 0, stream>>>(ga, gout, h0);
  // stage 1: T1 = tanh(h0@w1+b1), P1 = h0@pw+pb (fused, z=2)
  kgemm<<<dim3(8, 16, 2), 256, 0, stream>>>(h0, m1w1, m1b1, nullptr, T1, 1,
                                            m1pw, m1pb, nullptr, P1, 0, 512, 512, 832);
  kgemm<<<dim3(8, 16, 1), 256, 0, stream>>>(T1, m1w2, m1b2, P1, Hm, 0,
                                            nullptr, nullptr, nullptr, nullptr, 0, 512, 512, 512);
  kbnstats<<<8, 512, 0, stream>>>(Hm, bns);
  kbnapply<<<1024, 256, 0, stream>>>(Hm, bns, bn1g, bn1b, HB1);
  // stage 2
  kgemm<<<dim3(8, 16, 1), 256, 0, stream>>>(HB1, m2w1, m2b1, nullptr, T1, 1,
                                            nullptr, nullptr, nullptr, nullptr, 0, 512, 512, 512);
  kgemm<<<dim3(8, 16, 1), 256, 0, stream>>>(T1, m2w2, m2b2, HB1, H2, 0,
                                            nullptr, nullptr, nullptr, nullptr, 0, 512, 512, 512);
  kbnstats<<<8, 512, 0, stream>>>(H2, bns + 1024);
  kbnapply<<<1024, 256, 0, stream>>>(H2, bns + 1024, bn2g, bn2b, HB2);
  // stage 3: T3 = tanh(HB2@w1+b1), P3 = HB2@pw+pb (fused, z=2)
  kgemm<<<dim3(4, 16, 2), 256, 0, stream>>>(HB2, m3w1, m3b1, nullptr, T3, 1,
                                            m3pw, m3pb, nullptr, P3, 0, 512, 256, 512);
  kgemm<<<dim3(4, 16, 1), 256, 0, stream>>>(T3, m3w2, m3b2, P3, hout, 0,
                                            nullptr, nullptr, nullptr, nullptr, 0, 512, 256, 256);
}